// Round 11
// baseline (8311.124 us; speedup 1.0000x reference)
//
#include <hip/hip_runtime.h>
#include <cstdint>
#include <cstddef>

#define T_SEQ 2048
#define BATCH 16
#define DIM   512
#define HID   512
#define NCOL  2048            // 4H per direction
#define XROW  520             // 512 + 8 pad (bf16 elems)

typedef __attribute__((ext_vector_type(8))) short          s8v;
typedef __attribute__((ext_vector_type(4))) float          f4v;
typedef __attribute__((ext_vector_type(4))) unsigned short h4v;

#define HXBASE(d, s) (((size_t)((d) * 2 + (s)) * BATCH) * HID)

__device__ __forceinline__ unsigned short f2b(float f) {
  unsigned u = __builtin_bit_cast(unsigned, f);
  return (unsigned short)((u + 0x7fffu + ((u >> 16) & 1u)) >> 16);  // RNE
}

#define MFMA16(a, w, c) __builtin_amdgcn_mfma_f32_16x16x32_bf16((a), (w), (c), 0, 0, 0)

// grid = 64 wgs x 256 thr. wg w: dir = w>>5, j-block = (w&31)*16.
// R5 gate path (wave wv = gate wv, glds exchange, coalesced (b,sub)
// publish/out). This round attacks the exchange round-trip edges:
//  - x fragments preloaded to REGISTERS in the tail (step-head MFMAs have
//    zero LDS dependency; h ds_reads fly under the first 16 x-MFMAs)
//  - poll loads issued immediately after publish, BEFORE the out store
//    (vmcnt wait for the check no longer drains the HBM write)
//  - first poll retry without s_sleep
//  - x global loads + staging 2 steps ahead, fully inside the RT window
// h exchange: epoch-tagged bf16 u32 in d_ws, ping-pong slots, relaxed
// agent-scope ld/st, 2^14 guard (never hang).
__global__ __launch_bounds__(256, 1)
void lstm_persist(const float* __restrict__ x, const int* __restrict__ lengths,
                  const float* __restrict__ Wi_f, const float* __restrict__ Wh_f,
                  const float* __restrict__ b_f,
                  const float* __restrict__ Wi_b, const float* __restrict__ Wh_b,
                  const float* __restrict__ b_b,
                  unsigned int* __restrict__ hx,
                  float* __restrict__ out) {
  __shared__ unsigned short Ax[2][BATCH][XROW];  // x tiles, double-buffered
  __shared__ unsigned short Ah[BATCH][XROW];     // h(t-1) tile
  __shared__ float glds[4][BATCH][16];           // gate exchange

  const int w    = (int)blockIdx.x;
  const int dir  = w >> 5;
  const int j0   = (w & 31) * 16;
  const int tid  = (int)threadIdx.x;
  const int lane = tid & 63;
  const int wv   = tid >> 6;

  const int b   = tid >> 4;   // one (b, sub) per thread: staging, gates, publish
  const int sub = tid & 15;
  const int len = lengths[b];

  const float* bias = dir ? b_b : b_f;
  const float bi = bias[0 * HID + j0 + sub];
  const float bf = bias[1 * HID + j0 + sub];
  const float bg = bias[2 * HID + j0 + sub];
  const float bo = bias[3 * HID + j0 + sub];

  // ---- persistent W fragments (wave wv = gate wv) ----
  s8v wfi[16], wfh[16];
  {
    const float* Wi = dir ? Wi_b : Wi_f;
    const float* Wh = dir ? Wh_b : Wh_f;
    const int col = wv * HID + j0 + (lane & 15);
    const int kb  = (lane >> 4) * 8;
#pragma unroll
    for (int kc = 0; kc < 16; ++kc) {
      const float* src = Wi + (size_t)(kc * 32 + kb) * NCOL + col;
      s8v f;
#pragma unroll
      for (int j = 0; j < 8; ++j) f[j] = (short)f2b(src[(size_t)j * NCOL]);
      wfi[kc] = f;
    }
#pragma unroll
    for (int kc = 0; kc < 16; ++kc) {
      const float* src = Wh + (size_t)(kc * 32 + kb) * NCOL + col;
      s8v f;
#pragma unroll
      for (int j = 0; j < 8; ++j) f[j] = (short)f2b(src[(size_t)j * NCOL]);
      wfh[kc] = f;
    }
  }

  const int arow = lane & 15;
  const int koff = (lane >> 4) * 8;

  auto taus = [len, dir](int s) { return dir ? ((T_SEQ - 1 - s + len) & (T_SEQ - 1)) : s; };

  // ---- prologue: stage x(tau(0)) -> Ax[0], x(tau(1)) -> Ax[1] ----
  {
    const float* x0 = x + ((size_t)b * T_SEQ + taus(0)) * DIM;
    const float* x1 = x + ((size_t)b * T_SEQ + taus(1)) * DIM;
#pragma unroll
    for (int r = 0; r < 8; ++r) {
      const int k = sub * 4 + r * 64;
      f4v v0 = *(const f4v*)(x0 + k);
      f4v v1 = *(const f4v*)(x1 + k);
      h4v p0; p0[0] = f2b(v0[0]); p0[1] = f2b(v0[1]); p0[2] = f2b(v0[2]); p0[3] = f2b(v0[3]);
      h4v p1; p1[0] = f2b(v1[0]); p1[1] = f2b(v1[1]); p1[2] = f2b(v1[2]); p1[3] = f2b(v1[3]);
      *(h4v*)&Ax[0][b][k] = p0;
      *(h4v*)&Ax[1][b][k] = p1;
    }
  }
  __syncthreads();

  // ---- preload x(0) fragments into registers ----
  s8v xf[16];
#pragma unroll
  for (int kc = 0; kc < 16; ++kc)
    xf[kc] = *(const s8v*)(&Ax[0][arow][koff] + kc * 32);

  float c_state = 0.f;

  for (int t = 0; t < T_SEQ; ++t) {
    const unsigned e = (unsigned)(t + 1);
    const bool notlast = (t + 1 < T_SEQ);

    // ---- critical-path MFMA: x-frags from regs (no LDS dep), then h ----
    f4v acc;
    {
      f4v d0 = {0,0,0,0}, d1 = {0,0,0,0}, d2 = {0,0,0,0}, d3 = {0,0,0,0};
#pragma unroll
      for (int kc = 0; kc < 16; kc += 4) {
        d0 = MFMA16(xf[kc + 0], wfi[kc + 0], d0);
        d1 = MFMA16(xf[kc + 1], wfi[kc + 1], d1);
        d2 = MFMA16(xf[kc + 2], wfi[kc + 2], d2);
        d3 = MFMA16(xf[kc + 3], wfi[kc + 3], d3);
      }
      if (t > 0) {
        const unsigned short* ap = &Ah[arow][koff];
#pragma unroll
        for (int kc = 0; kc < 16; kc += 4) {
          d0 = MFMA16(*(const s8v*)(ap + (kc + 0) * 32), wfh[kc + 0], d0);
          d1 = MFMA16(*(const s8v*)(ap + (kc + 1) * 32), wfh[kc + 1], d1);
          d2 = MFMA16(*(const s8v*)(ap + (kc + 2) * 32), wfh[kc + 2], d2);
          d3 = MFMA16(*(const s8v*)(ap + (kc + 3) * 32), wfh[kc + 3], d3);
        }
      }
      acc = (d0 + d1) + (d2 + d3);
    }
#pragma unroll
    for (int r = 0; r < 4; ++r)
      glds[wv][(lane >> 4) * 4 + r][lane & 15] = acc[r];
    __syncthreads();   // SYNC-A: glds ready; Ah/Ax reads of this iter done

    // ---- gate math; publish h FIRST ----
    float h;
    {
      const float gi = glds[0][b][sub] + bi;
      const float gf = glds[1][b][sub] + bf;
      const float gg = glds[2][b][sub] + bg;
      const float go = glds[3][b][sub] + bo;
      const float si = 1.f / (1.f + __expf(-gi));
      const float sf = 1.f / (1.f + __expf(-gf));
      const float so = 1.f / (1.f + __expf(-go));
      const float tg = 1.f - 2.f / (1.f + __expf(2.f * gg));
      c_state = sf * c_state + si * tg;
      const float tc = 1.f - 2.f / (1.f + __expf(2.f * c_state));
      h = so * tc;
      if (notlast) {
        const unsigned tagged = ((unsigned)f2b(h) << 16) | e;
        __hip_atomic_store(&hx[HXBASE(dir, e & 1) + (size_t)b * HID + j0 + sub], tagged,
                           __ATOMIC_RELAXED, __HIP_MEMORY_SCOPE_AGENT);
      }
    }

    if (!notlast) {
      out[((size_t)b * T_SEQ + taus(t)) * (2 * HID) + (size_t)dir * HID + j0 + sub] = h;
      break;
    }

    // ---- poll loads for h(t): issued immediately after publish ----
    const unsigned* hrow = hx + HXBASE(dir, e & 1) + (size_t)b * HID;
    unsigned long long hu[16];
#pragma unroll
    for (int r = 0; r < 8; ++r) {
      const int k = sub * 4 + r * 64;
      hu[2*r]   = __hip_atomic_load((const unsigned long long*)(hrow + k),
                                    __ATOMIC_RELAXED, __HIP_MEMORY_SCOPE_AGENT);
      hu[2*r+1] = __hip_atomic_load((const unsigned long long*)(hrow + k) + 1,
                                    __ATOMIC_RELAXED, __HIP_MEMORY_SCOPE_AGENT);
    }

    // ---- out store (newest in vmcnt queue: not waited by the check) ----
    out[((size_t)b * T_SEQ + taus(t)) * (2 * HID) + (size_t)dir * HID + j0 + sub] = h;

    // ---- x(t+2) global loads (consumed below, covered by RT window) ----
    f4v xv[8];
    const bool havex2 = (t + 2 < T_SEQ);
    if (havex2) {
      const float* xr = x + ((size_t)b * T_SEQ + taus(t + 2)) * DIM;
#pragma unroll
      for (int r = 0; r < 8; ++r) xv[r] = *(const f4v*)(xr + sub * 4 + r * 64);
    }

    // ---- preload x(t+1) fragments into regs (off-path ds_reads) ----
#pragma unroll
    for (int kc = 0; kc < 16; ++kc)
      xf[kc] = *(const s8v*)(&Ax[(t + 1) & 1][arow][koff] + kc * 32);

    // ---- stage x(t+2) -> Ax[t&1] ----
    if (havex2) {
#pragma unroll
      for (int r = 0; r < 8; ++r) {
        const int k = sub * 4 + r * 64;
        h4v p; p[0] = f2b(xv[r][0]); p[1] = f2b(xv[r][1]);
               p[2] = f2b(xv[r][2]); p[3] = f2b(xv[r][3]);
        *(h4v*)&Ax[t & 1][b][k] = p;
      }
    }

    // ---- check tags; first retry immediate, then sleep; 2^14 guard ----
    {
      const unsigned long long msk = 0x0000FFFF0000FFFFULL;
      const unsigned long long pat = ((unsigned long long)e << 32) | e;
      int guard = 0;
      while (true) {
        bool ok = true;
#pragma unroll
        for (int r = 0; r < 16; ++r) ok &= ((hu[r] & msk) == pat);
        if (ok | (++guard > (1 << 14))) break;
        if (guard > 1) __builtin_amdgcn_s_sleep(1);
#pragma unroll
        for (int r = 0; r < 8; ++r) {
          const int k = sub * 4 + r * 64;
          hu[2*r]   = __hip_atomic_load((const unsigned long long*)(hrow + k),
                                        __ATOMIC_RELAXED, __HIP_MEMORY_SCOPE_AGENT);
          hu[2*r+1] = __hip_atomic_load((const unsigned long long*)(hrow + k) + 1,
                                        __ATOMIC_RELAXED, __HIP_MEMORY_SCOPE_AGENT);
        }
      }
    }

    // ---- stage h(t) -> Ah ----
#pragma unroll
    for (int r = 0; r < 8; ++r) {
      const int k = sub * 4 + r * 64;
      h4v p;
      p[0] = (unsigned short)(hu[2*r]   >> 16);
      p[1] = (unsigned short)(hu[2*r]   >> 48);
      p[2] = (unsigned short)(hu[2*r+1] >> 16);
      p[3] = (unsigned short)(hu[2*r+1] >> 48);
      *(h4v*)&Ah[b][k] = p;
    }
    __syncthreads();   // SYNC-B: Ah + Ax staged, xf regs ready
  }
}

extern "C" void kernel_launch(void* const* d_in, const int* in_sizes, int n_in,
                              void* d_out, int out_size, void* d_ws, size_t ws_size,
                              hipStream_t stream) {
  const float* x    = (const float*)d_in[0];
  const int*   len  = (const int*)d_in[1];
  const float* Wi_f = (const float*)d_in[2];
  const float* Wh_f = (const float*)d_in[3];
  const float* b_f  = (const float*)d_in[4];
  const float* Wi_b = (const float*)d_in[5];
  const float* Wh_b = (const float*)d_in[6];
  const float* b_b  = (const float*)d_in[7];
  float* out = (float*)d_out;
  unsigned int* hx = (unsigned int*)d_ws;   // [2][2][16][512] u32 = 128 KiB

  hipMemsetAsync(d_ws, 0, (size_t)2 * 2 * BATCH * HID * 4, stream);
  hipLaunchKernelGGL(lstm_persist, dim3(64), dim3(256), 0, stream,
                     x, len, Wi_f, Wh_f, b_f, Wi_b, Wh_b, b_b, hx, out);
}

// Round 12
// 5240.882 us; speedup vs baseline: 1.5858x; 1.5858x over previous
//
#include <hip/hip_runtime.h>
#include <cstdint>
#include <cstddef>

#define T_SEQ 2048
#define BATCH 16
#define DIM   512
#define HID   512
#define KTOT  1024            // D + H
#define NCOL  2048            // 4H per direction
#define APAD  8
#define AROW  (KTOT + APAD)   // 1032 bf16 elems per A row

typedef __attribute__((ext_vector_type(8))) short          s8v;
typedef __attribute__((ext_vector_type(4))) float          f4v;
typedef __attribute__((ext_vector_type(4))) unsigned short h4v;

#define HXBASE(d, s) (((size_t)((d) * 2 + (s)) * BATCH) * HID)

__device__ __forceinline__ unsigned short f2b(float f) {
  unsigned u = __builtin_bit_cast(unsigned, f);
  return (unsigned short)((u + 0x7fffu + ((u >> 16) & 1u)) >> 16);  // RNE
}

// grid = 64 wgs x 256 thr. wg w: dir = w>>5, j-block = (w&31)*16.
// EXACT R5 structure (best: 5.72ms / 2.79us/step) + ONE change:
// a calibrated s_sleep(8) before the first poll sample. Rationale: a load
// samples memory at ISSUE time; R5's first sample went out ~0.2us after
// publish (stale -> guaranteed miss -> +0.9us retry round). Delaying the
// first sample ~0.21us lets it return the just-visible h, saving a round.
// h exchange: epoch-tagged bf16 u32 in d_ws, ping-pong slots, relaxed
// agent-scope ld/st, in-loop sample-then-check poll (R11 lesson: never
// early-issue/late-check), 2^14 guard (never hang).
__global__ __launch_bounds__(256, 1)
void lstm_persist(const float* __restrict__ x, const int* __restrict__ lengths,
                  const float* __restrict__ Wi_f, const float* __restrict__ Wh_f,
                  const float* __restrict__ b_f,
                  const float* __restrict__ Wi_b, const float* __restrict__ Wh_b,
                  const float* __restrict__ b_b,
                  unsigned int* __restrict__ hx,
                  float* __restrict__ out) {
  __shared__ unsigned short A[BATCH][AROW];   // [b][ x(0..512) | h(512..1024) ]
  __shared__ float glds[4][BATCH][16];        // gate exchange

  const int w    = (int)blockIdx.x;
  const int dir  = w >> 5;
  const int j0   = (w & 31) * 16;
  const int tid  = (int)threadIdx.x;
  const int lane = tid & 63;
  const int wv   = tid >> 6;
  const int b    = tid >> 4;   // one (b, sub) per thread
  const int sub  = tid & 15;
  const int len  = lengths[b];

  const float* bias = dir ? b_b : b_f;
  const float bi = bias[0 * HID + j0 + sub];
  const float bf = bias[1 * HID + j0 + sub];
  const float bg = bias[2 * HID + j0 + sub];
  const float bo = bias[3 * HID + j0 + sub];

  // ---- persistent W fragments (wave wv = gate wv), fp32 -> bf16 ----
  s8v wf[32];
  {
    const float* Wi = dir ? Wi_b : Wi_f;
    const float* Wh = dir ? Wh_b : Wh_f;
    const int col = wv * HID + j0 + (lane & 15);
    const int kb  = (lane >> 4) * 8;
#pragma unroll
    for (int kc = 0; kc < 16; ++kc) {
      const float* src = Wi + (size_t)(kc * 32 + kb) * NCOL + col;
      s8v f;
#pragma unroll
      for (int j = 0; j < 8; ++j) f[j] = (short)f2b(src[(size_t)j * NCOL]);
      wf[kc] = f;
    }
#pragma unroll
    for (int kc = 0; kc < 16; ++kc) {
      const float* src = Wh + (size_t)(kc * 32 + kb) * NCOL + col;
      s8v f;
#pragma unroll
      for (int j = 0; j < 8; ++j) f[j] = (short)f2b(src[(size_t)j * NCOL]);
      wf[16 + kc] = f;
    }
  }

  float c_state = 0.f;
  const int arow = lane & 15;
  const int koff = (lane >> 4) * 8;

  // ---- prologue: stage A = [x_tau(0) | 0] ----
  {
    const int tau0 = dir ? ((T_SEQ - 1 + len) & (T_SEQ - 1)) : 0;
    const float* xrow = x + ((size_t)b * T_SEQ + tau0) * DIM;
#pragma unroll
    for (int r = 0; r < 8; ++r) {
      const int k = sub * 4 + r * 64;
      f4v v = *(const f4v*)(xrow + k);
      h4v p; p[0] = f2b(v[0]); p[1] = f2b(v[1]); p[2] = f2b(v[2]); p[3] = f2b(v[3]);
      *(h4v*)&A[b][k] = p;
      h4v z = (h4v){0, 0, 0, 0};
      *(h4v*)&A[b][DIM + k] = z;
    }
  }
  __syncthreads();

  for (int t = 0; t < T_SEQ; ++t) {
    const unsigned e = (unsigned)(t + 1);
    const bool notlast = (t + 1 < T_SEQ);

    // ---- prefetch x(t+1): latency hides under MFMA + gates ----
    f4v xv[8];
    if (notlast) {
      const int taun = dir ? ((T_SEQ - 2 - t + len) & (T_SEQ - 1)) : (t + 1);
      const float* xrow = x + ((size_t)b * T_SEQ + taun) * DIM;
#pragma unroll
      for (int r = 0; r < 8; ++r) xv[r] = *(const f4v*)(xrow + sub * 4 + r * 64);
    }

    // ---- MFMA: 16x16 gate tile over K=1024, 4 chains ----
    f4v acc;
    {
      f4v d0 = {0,0,0,0}, d1 = {0,0,0,0}, d2 = {0,0,0,0}, d3 = {0,0,0,0};
      const unsigned short* ap = &A[arow][koff];
#pragma unroll
      for (int kc = 0; kc < 32; kc += 4) {
        d0 = __builtin_amdgcn_mfma_f32_16x16x32_bf16(*(const s8v*)(ap + (kc + 0) * 32), wf[kc + 0], d0, 0, 0, 0);
        d1 = __builtin_amdgcn_mfma_f32_16x16x32_bf16(*(const s8v*)(ap + (kc + 1) * 32), wf[kc + 1], d1, 0, 0, 0);
        d2 = __builtin_amdgcn_mfma_f32_16x16x32_bf16(*(const s8v*)(ap + (kc + 2) * 32), wf[kc + 2], d2, 0, 0, 0);
        d3 = __builtin_amdgcn_mfma_f32_16x16x32_bf16(*(const s8v*)(ap + (kc + 3) * 32), wf[kc + 3], d3, 0, 0, 0);
      }
      acc = (d0 + d1) + (d2 + d3);
    }
#pragma unroll
    for (int r = 0; r < 4; ++r)
      glds[wv][(lane >> 4) * 4 + r][lane & 15] = acc[r];
    __syncthreads();   // A consumed; glds ready

    // ---- fp32 gate math; publish tagged h first, then plain out store ----
    {
      const float gi = glds[0][b][sub] + bi;
      const float gf = glds[1][b][sub] + bf;
      const float gg = glds[2][b][sub] + bg;
      const float go = glds[3][b][sub] + bo;
      const float si = 1.f / (1.f + __expf(-gi));
      const float sf = 1.f / (1.f + __expf(-gf));
      const float so = 1.f / (1.f + __expf(-go));
      const float tg = 1.f - 2.f / (1.f + __expf(2.f * gg));
      c_state = sf * c_state + si * tg;
      const float tc = 1.f - 2.f / (1.f + __expf(2.f * c_state));
      const float h = so * tc;
      const int tau = dir ? ((T_SEQ - 1 - t + len) & (T_SEQ - 1)) : t;
      if (notlast) {
        const unsigned tagged = ((unsigned)f2b(h) << 16) | e;
        __hip_atomic_store(&hx[HXBASE(dir, e & 1) + (size_t)b * HID + j0 + sub], tagged,
                           __ATOMIC_RELAXED, __HIP_MEMORY_SCOPE_AGENT);
      }
      out[((size_t)b * T_SEQ + tau) * (2 * HID) + (size_t)dir * HID + j0 + sub] = h;
    }

    if (!notlast) break;

    // ---- stage x(t+1) into A (x part; A free after the sync above) ----
#pragma unroll
    for (int r = 0; r < 8; ++r) {
      const int k = sub * 4 + r * 64;
      h4v p; p[0] = f2b(xv[r][0]); p[1] = f2b(xv[r][1]);
             p[2] = f2b(xv[r][2]); p[3] = f2b(xv[r][3]);
      *(h4v*)&A[b][k] = p;
    }

    // ---- calibrated delay: first sample must not be stale (R11 lesson:
    //      loads sample at issue time; publish needs ~0.45us to the LLC) ----
    __builtin_amdgcn_s_sleep(8);

    // ---- poll h(t): in-loop sample-then-check; 2^14 guard ----
    const unsigned* hrow = hx + HXBASE(dir, e & 1) + (size_t)b * HID;
    const unsigned long long msk = 0x0000FFFF0000FFFFULL;
    const unsigned long long pat = ((unsigned long long)e << 32) | e;
    unsigned long long hu[16];
    {
      int guard = 0;
      while (true) {
        bool ok = true;
#pragma unroll
        for (int r = 0; r < 8; ++r) {
          const int k = sub * 4 + r * 64;
          hu[2 * r]     = __hip_atomic_load((const unsigned long long*)(hrow + k),
                                            __ATOMIC_RELAXED, __HIP_MEMORY_SCOPE_AGENT);
          hu[2 * r + 1] = __hip_atomic_load((const unsigned long long*)(hrow + k) + 1,
                                            __ATOMIC_RELAXED, __HIP_MEMORY_SCOPE_AGENT);
          ok &= ((hu[2 * r] & msk) == pat) & ((hu[2 * r + 1] & msk) == pat);
        }
        if (ok | (++guard > (1 << 14))) break;
        __builtin_amdgcn_s_sleep(1);
      }
    }

    // ---- stage h(t) -> A (h part) ----
#pragma unroll
    for (int r = 0; r < 8; ++r) {
      const int k = sub * 4 + r * 64;
      h4v p;
      p[0] = (unsigned short)(hu[2 * r]     >> 16);
      p[1] = (unsigned short)(hu[2 * r]     >> 48);
      p[2] = (unsigned short)(hu[2 * r + 1] >> 16);
      p[3] = (unsigned short)(hu[2 * r + 1] >> 48);
      *(h4v*)&A[b][DIM + k] = p;
    }
    __syncthreads();   // A ready for next MFMA
  }
}

extern "C" void kernel_launch(void* const* d_in, const int* in_sizes, int n_in,
                              void* d_out, int out_size, void* d_ws, size_t ws_size,
                              hipStream_t stream) {
  const float* x    = (const float*)d_in[0];
  const int*   len  = (const int*)d_in[1];
  const float* Wi_f = (const float*)d_in[2];
  const float* Wh_f = (const float*)d_in[3];
  const float* b_f  = (const float*)d_in[4];
  const float* Wi_b = (const float*)d_in[5];
  const float* Wh_b = (const float*)d_in[6];
  const float* b_b  = (const float*)d_in[7];
  float* out = (float*)d_out;
  unsigned int* hx = (unsigned int*)d_ws;   // [2][2][16][512] u32 = 128 KiB

  hipMemsetAsync(d_ws, 0, (size_t)2 * 2 * BATCH * HID * 4, stream);
  hipLaunchKernelGGL(lstm_persist, dim3(64), dim3(256), 0, stream,
                     x, len, Wi_f, Wh_f, b_f, Wi_b, Wh_b, b_b, hx, out);
}

// Round 13
// 5195.689 us; speedup vs baseline: 1.5996x; 1.0087x over previous
//
#include <hip/hip_runtime.h>
#include <cstdint>
#include <cstddef>

#define T_SEQ 2048
#define BATCH 16
#define DIM   512
#define HID   512
#define KTOT  1024            // D + H
#define NCOL  2048            // 4H per direction
#define APAD  8
#define AROW  (KTOT + APAD)   // 1032 bf16 elems per A row

typedef __attribute__((ext_vector_type(8))) short          s8v;
typedef __attribute__((ext_vector_type(4))) float          f4v;
typedef __attribute__((ext_vector_type(4))) unsigned short h4v;

#define HXBASE(d, s) (((size_t)((d) * 2 + (s)) * BATCH) * HID)

__device__ __forceinline__ unsigned short f2b(float f) {
  unsigned u = __builtin_bit_cast(unsigned, f);
  return (unsigned short)((u + 0x7fffu + ((u >> 16) & 1u)) >> 16);  // RNE
}

// grid = 64 wgs x 256 thr. wg w: dir = w>>5, j-block = (w&31)*16.
// R12 structure (5.24ms / 2.56us/step) + ONE change: the poll retry loop
// no longer sleeps — a re-sample round's own ~0.4us LLC RT is natural
// pacing, and continuous sampling halves expected detection delay after
// the slowest producer's publish becomes visible. Initial calibrated
// s_sleep(8) kept (R12-proven: first sample must not be stale).
// h exchange: epoch-tagged bf16 u32 in d_ws, ping-pong slots, relaxed
// agent-scope ld/st, in-loop sample-then-check poll, 2^14 guard.
__global__ __launch_bounds__(256, 1)
void lstm_persist(const float* __restrict__ x, const int* __restrict__ lengths,
                  const float* __restrict__ Wi_f, const float* __restrict__ Wh_f,
                  const float* __restrict__ b_f,
                  const float* __restrict__ Wi_b, const float* __restrict__ Wh_b,
                  const float* __restrict__ b_b,
                  unsigned int* __restrict__ hx,
                  float* __restrict__ out) {
  __shared__ unsigned short A[BATCH][AROW];   // [b][ x(0..512) | h(512..1024) ]
  __shared__ float glds[4][BATCH][16];        // gate exchange

  const int w    = (int)blockIdx.x;
  const int dir  = w >> 5;
  const int j0   = (w & 31) * 16;
  const int tid  = (int)threadIdx.x;
  const int lane = tid & 63;
  const int wv   = tid >> 6;
  const int b    = tid >> 4;   // one (b, sub) per thread
  const int sub  = tid & 15;
  const int len  = lengths[b];

  const float* bias = dir ? b_b : b_f;
  const float bi = bias[0 * HID + j0 + sub];
  const float bf = bias[1 * HID + j0 + sub];
  const float bg = bias[2 * HID + j0 + sub];
  const float bo = bias[3 * HID + j0 + sub];

  // ---- persistent W fragments (wave wv = gate wv), fp32 -> bf16 ----
  s8v wf[32];
  {
    const float* Wi = dir ? Wi_b : Wi_f;
    const float* Wh = dir ? Wh_b : Wh_f;
    const int col = wv * HID + j0 + (lane & 15);
    const int kb  = (lane >> 4) * 8;
#pragma unroll
    for (int kc = 0; kc < 16; ++kc) {
      const float* src = Wi + (size_t)(kc * 32 + kb) * NCOL + col;
      s8v f;
#pragma unroll
      for (int j = 0; j < 8; ++j) f[j] = (short)f2b(src[(size_t)j * NCOL]);
      wf[kc] = f;
    }
#pragma unroll
    for (int kc = 0; kc < 16; ++kc) {
      const float* src = Wh + (size_t)(kc * 32 + kb) * NCOL + col;
      s8v f;
#pragma unroll
      for (int j = 0; j < 8; ++j) f[j] = (short)f2b(src[(size_t)j * NCOL]);
      wf[16 + kc] = f;
    }
  }

  float c_state = 0.f;
  const int arow = lane & 15;
  const int koff = (lane >> 4) * 8;

  // ---- prologue: stage A = [x_tau(0) | 0] ----
  {
    const int tau0 = dir ? ((T_SEQ - 1 + len) & (T_SEQ - 1)) : 0;
    const float* xrow = x + ((size_t)b * T_SEQ + tau0) * DIM;
#pragma unroll
    for (int r = 0; r < 8; ++r) {
      const int k = sub * 4 + r * 64;
      f4v v = *(const f4v*)(xrow + k);
      h4v p; p[0] = f2b(v[0]); p[1] = f2b(v[1]); p[2] = f2b(v[2]); p[3] = f2b(v[3]);
      *(h4v*)&A[b][k] = p;
      h4v z = (h4v){0, 0, 0, 0};
      *(h4v*)&A[b][DIM + k] = z;
    }
  }
  __syncthreads();

  for (int t = 0; t < T_SEQ; ++t) {
    const unsigned e = (unsigned)(t + 1);
    const bool notlast = (t + 1 < T_SEQ);

    // ---- prefetch x(t+1): latency hides under MFMA + gates ----
    f4v xv[8];
    if (notlast) {
      const int taun = dir ? ((T_SEQ - 2 - t + len) & (T_SEQ - 1)) : (t + 1);
      const float* xrow = x + ((size_t)b * T_SEQ + taun) * DIM;
#pragma unroll
      for (int r = 0; r < 8; ++r) xv[r] = *(const f4v*)(xrow + sub * 4 + r * 64);
    }

    // ---- MFMA: 16x16 gate tile over K=1024, 4 chains ----
    f4v acc;
    {
      f4v d0 = {0,0,0,0}, d1 = {0,0,0,0}, d2 = {0,0,0,0}, d3 = {0,0,0,0};
      const unsigned short* ap = &A[arow][koff];
#pragma unroll
      for (int kc = 0; kc < 32; kc += 4) {
        d0 = __builtin_amdgcn_mfma_f32_16x16x32_bf16(*(const s8v*)(ap + (kc + 0) * 32), wf[kc + 0], d0, 0, 0, 0);
        d1 = __builtin_amdgcn_mfma_f32_16x16x32_bf16(*(const s8v*)(ap + (kc + 1) * 32), wf[kc + 1], d1, 0, 0, 0);
        d2 = __builtin_amdgcn_mfma_f32_16x16x32_bf16(*(const s8v*)(ap + (kc + 2) * 32), wf[kc + 2], d2, 0, 0, 0);
        d3 = __builtin_amdgcn_mfma_f32_16x16x32_bf16(*(const s8v*)(ap + (kc + 3) * 32), wf[kc + 3], d3, 0, 0, 0);
      }
      acc = (d0 + d1) + (d2 + d3);
    }
#pragma unroll
    for (int r = 0; r < 4; ++r)
      glds[wv][(lane >> 4) * 4 + r][lane & 15] = acc[r];
    __syncthreads();   // A consumed; glds ready

    // ---- fp32 gate math; publish tagged h first, then plain out store ----
    {
      const float gi = glds[0][b][sub] + bi;
      const float gf = glds[1][b][sub] + bf;
      const float gg = glds[2][b][sub] + bg;
      const float go = glds[3][b][sub] + bo;
      const float si = 1.f / (1.f + __expf(-gi));
      const float sf = 1.f / (1.f + __expf(-gf));
      const float so = 1.f / (1.f + __expf(-go));
      const float tg = 1.f - 2.f / (1.f + __expf(2.f * gg));
      c_state = sf * c_state + si * tg;
      const float tc = 1.f - 2.f / (1.f + __expf(2.f * c_state));
      const float h = so * tc;
      const int tau = dir ? ((T_SEQ - 1 - t + len) & (T_SEQ - 1)) : t;
      if (notlast) {
        const unsigned tagged = ((unsigned)f2b(h) << 16) | e;
        __hip_atomic_store(&hx[HXBASE(dir, e & 1) + (size_t)b * HID + j0 + sub], tagged,
                           __ATOMIC_RELAXED, __HIP_MEMORY_SCOPE_AGENT);
      }
      out[((size_t)b * T_SEQ + tau) * (2 * HID) + (size_t)dir * HID + j0 + sub] = h;
    }

    if (!notlast) break;

    // ---- stage x(t+1) into A (x part; A free after the sync above) ----
#pragma unroll
    for (int r = 0; r < 8; ++r) {
      const int k = sub * 4 + r * 64;
      h4v p; p[0] = f2b(xv[r][0]); p[1] = f2b(xv[r][1]);
             p[2] = f2b(xv[r][2]); p[3] = f2b(xv[r][3]);
      *(h4v*)&A[b][k] = p;
    }

    // ---- calibrated delay: first sample must not be stale ----
    __builtin_amdgcn_s_sleep(8);

    // ---- poll h(t): continuous sample-then-check (no retry sleep);
    //      the round's own ~0.4us LLC RT is the pacing. 2^14 guard. ----
    const unsigned* hrow = hx + HXBASE(dir, e & 1) + (size_t)b * HID;
    const unsigned long long msk = 0x0000FFFF0000FFFFULL;
    const unsigned long long pat = ((unsigned long long)e << 32) | e;
    unsigned long long hu[16];
    {
      int guard = 0;
      while (true) {
        bool ok = true;
#pragma unroll
        for (int r = 0; r < 8; ++r) {
          const int k = sub * 4 + r * 64;
          hu[2 * r]     = __hip_atomic_load((const unsigned long long*)(hrow + k),
                                            __ATOMIC_RELAXED, __HIP_MEMORY_SCOPE_AGENT);
          hu[2 * r + 1] = __hip_atomic_load((const unsigned long long*)(hrow + k) + 1,
                                            __ATOMIC_RELAXED, __HIP_MEMORY_SCOPE_AGENT);
          ok &= ((hu[2 * r] & msk) == pat) & ((hu[2 * r + 1] & msk) == pat);
        }
        if (ok | (++guard > (1 << 14))) break;
      }
    }

    // ---- stage h(t) -> A (h part) ----
#pragma unroll
    for (int r = 0; r < 8; ++r) {
      const int k = sub * 4 + r * 64;
      h4v p;
      p[0] = (unsigned short)(hu[2 * r]     >> 16);
      p[1] = (unsigned short)(hu[2 * r]     >> 48);
      p[2] = (unsigned short)(hu[2 * r + 1] >> 16);
      p[3] = (unsigned short)(hu[2 * r + 1] >> 48);
      *(h4v*)&A[b][DIM + k] = p;
    }
    __syncthreads();   // A ready for next MFMA
  }
}

extern "C" void kernel_launch(void* const* d_in, const int* in_sizes, int n_in,
                              void* d_out, int out_size, void* d_ws, size_t ws_size,
                              hipStream_t stream) {
  const float* x    = (const float*)d_in[0];
  const int*   len  = (const int*)d_in[1];
  const float* Wi_f = (const float*)d_in[2];
  const float* Wh_f = (const float*)d_in[3];
  const float* b_f  = (const float*)d_in[4];
  const float* Wi_b = (const float*)d_in[5];
  const float* Wh_b = (const float*)d_in[6];
  const float* b_b  = (const float*)d_in[7];
  float* out = (float*)d_out;
  unsigned int* hx = (unsigned int*)d_ws;   // [2][2][16][512] u32 = 128 KiB

  hipMemsetAsync(d_ws, 0, (size_t)2 * 2 * BATCH * HID * 4, stream);
  hipLaunchKernelGGL(lstm_persist, dim3(64), dim3(256), 0, stream,
                     x, len, Wi_f, Wh_f, b_f, Wi_b, Wh_b, b_b, hx, out);
}